// Round 3
// baseline (3954.512 us; speedup 1.0000x reference)
//
#include <hip/hip_runtime.h>
#include <stdint.h>

namespace {

constexpr int H = 512;
constexpr int V = 64;     // vocab incl. think-end
constexpr int B = 8;
constexpr int T = 48;
constexpr int D1 = 49;    // delay slots
constexpr int P = 4;      // i-partitions (deterministic split reduction)
constexpr int CH = H / P; // 128
constexpr int NDEC = 45;  // N = T-3
constexpr int NIT = 9 + NDEC; // think iters + decode iters = 54

// ws layout (in floats)
constexpr size_t SZ_BUF   = (size_t)P * D1 * B * H;          // 802816
constexpr size_t OFF_BUF  = 0;
constexpr size_t OFF_HACT = OFF_BUF + SZ_BUF;                // B*H
constexpr size_t OFF_CUR  = OFF_HACT + (size_t)B * H;        // B*V
constexpr size_t OFF_NOISE= OFF_CUR + (size_t)B * V;         // B*NIT*V
constexpr size_t OFF_INT  = OFF_NOISE + (size_t)B * NIT * V; // int region
// ints: [0..7]=ptr_s  [8..15]=done  [16..23]=sc_active  [24..31]=sc_base

__device__ __forceinline__ void tf2x32(uint32_t k0, uint32_t k1,
                                       uint32_t& x0, uint32_t& x1) {
  const uint32_t ks2 = k0 ^ k1 ^ 0x1BD11BDAu;
  x0 += k0; x1 += k1;
#define RR(r) { x0 += x1; x1 = (x1 << (r)) | (x1 >> (32-(r))); x1 ^= x0; }
  RR(13) RR(15) RR(26) RR(6)  x0 += k1;  x1 += ks2 + 1u;
  RR(17) RR(29) RR(16) RR(24) x0 += ks2; x1 += k0 + 2u;
  RR(13) RR(15) RR(26) RR(6)  x0 += k0;  x1 += k1 + 3u;
  RR(17) RR(29) RR(16) RR(24) x0 += k1;  x1 += ks2 + 4u;
  RR(13) RR(15) RR(26) RR(6)  x0 += ks2; x1 += k0 + 5u;
#undef RR
}

__device__ __forceinline__ float gumbel_from_bits(uint32_t bits) {
  // JAX uniform(minval=1e-9, maxval=1.0) in f32: (1.0f-1e-9f)==1.0f exactly,
  // so u = bitcast((bits>>9)|0x3f800000) - 1.0f; r = u + 1e-9f; max is no-op.
  float u = __uint_as_float((bits >> 9) | 0x3F800000u) - 1.0f;
  u = u + 1e-9f;
  return -logf(-logf(u));   // logits = y + this
}

// ---------------- init: zero buf, RNG table, cur/ptr/done ----------------
__global__ __launch_bounds__(256) void k_init(const float* __restrict__ x,
                                              float* __restrict__ ws) {
  float* bufP  = ws + OFF_BUF;
  float* cur   = ws + OFF_CUR;
  float* noise = ws + OFF_NOISE;
  int*   ib    = (int*)(ws + OFF_INT);
  int tid = blockIdx.x * 256 + threadIdx.x;

  for (size_t i = (size_t)tid; i < SZ_BUF; i += 256u * 256u) bufP[i] = 0.0f;

  // noise via PARTITIONABLE threefry (jax_threefry_partitionable=True default
  // in recent JAX):
  //   keys[s]   = threefry(key(0,42), (0, s))      (both output words)
  //   iter key  = threefry(keys[s], (0, data))     (fold_in, both words)
  //   bits[j]   = w0 ^ w1 of threefry(iterkey, (0, j))  (partitionable
  //               random_bits XORs the two output words for bit_width=32)
  if (tid < B * NIT * V) {   // 27648 threads: one per (s, it, j)
    int j = tid & 63; int rest = tid >> 6;
    int it = rest % NIT; int s = rest / NIT;
    uint32_t ka = 0u, kb = (uint32_t)s;
    tf2x32(0u, 42u, ka, kb);                 // split -> key_s
    uint32_t data = (it < 9) ? (uint32_t)it : (uint32_t)(10000 + (it - 9));
    uint32_t e = 0u, f = data;
    tf2x32(ka, kb, e, f);                    // fold_in -> iter key
    uint32_t x0 = 0u, x1 = (uint32_t)j;
    tf2x32(e, f, x0, x1);                    // counter-mode block
    noise[((size_t)s * NIT + it) * V + j] = gumbel_from_bits(x0 ^ x1);
  }

  // cur init = x[:, T-1, :]
  if (tid >= 32768 && tid < 32768 + B * V) {
    int v2 = tid - 32768; int b = v2 >> 6; int o = v2 & 63;
    cur[v2] = x[((size_t)b * T + (T - 1)) * V + o];
  }
  if (tid >= 33792 && tid < 33792 + B) {
    int s = tid - 33792;
    ib[s] = T % D1;   // ptr after encoder = 48
    ib[8 + s] = 0;    // done = false
  }
}

// ---------------- encoder activation: h = tanh(x_t@wa.T + ba + h_del) ----
__global__ __launch_bounds__(256) void k_act_enc(const float* __restrict__ x,
    const float* __restrict__ wa, const float* __restrict__ ba,
    float* __restrict__ ws, int t) {
  float* bufP = ws + OFF_BUF;
  float* hact = ws + OFF_HACT;
  int b = blockIdx.x;
  int ptr = t % D1;
  const float* xr = x + ((size_t)b * T + t) * V;
  for (int i = threadIdx.x; i < H; i += 256) {
    float hd = 0.0f;
    #pragma unroll
    for (int p = 0; p < P; ++p) {
      float* q = &bufP[(((size_t)p * D1 + ptr) * B + b) * H + i];
      hd += *q; *q = 0.0f;           // read h_del partial, clear slot
    }
    float acc = ba[i] + hd;
    const float* war = wa + (size_t)i * V;
    #pragma unroll
    for (int v = 0; v < V; v += 4) {
      float4 w4 = *(const float4*)(war + v);
      float4 x4 = *(const float4*)(xr + v);
      acc = fmaf(w4.x, x4.x, acc); acc = fmaf(w4.y, x4.y, acc);
      acc = fmaf(w4.z, x4.z, acc); acc = fmaf(w4.w, x4.w, acc);
    }
    hact[(size_t)b * H + i] = tanhf(acc);
  }
}

// ---------------- scatter: buf[(base+d)%49][b][ho] += sum_i cm[d,ho,i]*h[b,i]
__global__ __launch_bounds__(256) void k_scat(const float* __restrict__ tau,
    const float* __restrict__ lat, float* __restrict__ ws, int enc_ptr) {
  float* bufP = ws + OFF_BUF;
  const float* hact = ws + OFF_HACT;
  const int* ib = (const int*)(ws + OFF_INT);
  int unit = blockIdx.x * 4 + (threadIdx.x >> 6);  // 2048 wave-units
  int lane = threadIdx.x & 63;
  int ho = unit & (H - 1);
  int p  = unit >> 9;
  const float dd = (float)lane;
  const float inv = 1.0f / 24.0f;
  const float inv2 = inv * inv;
  float acc[B];
  #pragma unroll
  for (int b = 0; b < B; ++b) acc[b] = 0.0f;
  const float* taur = tau + (size_t)ho * H + p * CH;
  const float* latr = lat + (size_t)ho * H + p * CH;
  const float* hr   = hact + p * CH;
  for (int ii = 0; ii < CH; ii += 4) {
    float4 t4 = *(const float4*)(taur + ii);
    float4 l4 = *(const float4*)(latr + ii);
    float4 h4[B];
    #pragma unroll
    for (int b = 0; b < B; ++b) h4[b] = *(const float4*)(hr + (size_t)b * H + ii);
    const float* tp = (const float*)&t4;
    const float* lp = (const float*)&l4;
    #pragma unroll
    for (int k = 0; k < 4; ++k) {
      float tc = fminf(fmaxf(tp[k], 1.0f), 48.0f);
      // match reference rounding exactly: mul -> abs -> sub (abs blocks fma)
      float cr = fmaxf(0.0f, inv - fabsf((dd - tc) * inv2));
      float q  = cr * lp[k];
      #pragma unroll
      for (int b = 0; b < B; ++b)
        acc[b] = fmaf(q, ((const float*)&h4[b])[k], acc[b]);
    }
  }
  if (lane >= 1 && lane <= 48) {
    #pragma unroll
    for (int b = 0; b < B; ++b) {
      int act, base;
      if (enc_ptr >= 0) { act = 1; base = enc_ptr; }
      else { act = ib[16 + b]; base = ib[24 + b]; }
      if (act) {
        int slot = base + lane; if (slot >= D1) slot -= D1;
        bufP[(((size_t)p * D1 + slot) * B + b) * H + ho] += acc[b];
      }
    }
  }
}

// ---------------- decode/think control step (one block per sample) -------
__global__ __launch_bounds__(256) void k_act_dec(const float* __restrict__ wa,
    const float* __restrict__ ba, const float* __restrict__ we,
    const float* __restrict__ be, float* __restrict__ ws,
    float* __restrict__ out, int iter, int mode /*0=think,1=decode*/, int j) {
  float* bufP = ws + OFF_BUF;
  float* hact = ws + OFF_HACT;
  float* cur  = ws + OFF_CUR;
  const float* noise = ws + OFF_NOISE;
  int* ib = (int*)(ws + OFF_INT);
  int b = blockIdx.x;
  __shared__ float hdel[H];
  __shared__ float curold[V];
  __shared__ float yv[V];
  __shared__ float red[256];
  __shared__ int s_idx;
  int ptr = ib[b];
  int dn  = ib[8 + b];
  int active = (mode == 1) ? 1 : (dn ? 0 : 1);

  if (threadIdx.x < V) curold[threadIdx.x] = cur[b * V + threadIdx.x];
  for (int i = threadIdx.x; i < H; i += 256) {
    float hd = 0.0f;
    #pragma unroll
    for (int p = 0; p < P; ++p) {
      float* q = &bufP[(((size_t)p * D1 + ptr) * B + b) * H + i];
      hd += *q;
      if (active) *q = 0.0f;
    }
    hdel[i] = hd;
  }
  __syncthreads();

  // h = tanh(wa@cur_old + ba + h_del)  (uses cur BEFORE this step's gumbel)
  for (int i = threadIdx.x; i < H; i += 256) {
    float acc = ba[i] + hdel[i];
    const float* war = wa + (size_t)i * V;
    #pragma unroll
    for (int v = 0; v < V; v += 4) {
      float4 w4 = *(const float4*)(war + v);
      acc = fmaf(w4.x, curold[v],     acc);
      acc = fmaf(w4.y, curold[v + 1], acc);
      acc = fmaf(w4.z, curold[v + 2], acc);
      acc = fmaf(w4.w, curold[v + 3], acc);
    }
    hact[(size_t)b * H + i] = tanhf(acc);
  }

  // y = we @ h_del + be  (4 partials per output)
  {
    int o = threadIdx.x >> 2, q = threadIdx.x & 3;
    const float* wer = we + (size_t)o * H + q * CH;
    const float* hp  = hdel + q * CH;
    float acc = 0.0f;
    for (int i2 = 0; i2 < CH; i2 += 4) {
      float4 w4 = *(const float4*)(wer + i2);
      acc = fmaf(w4.x, hp[i2],     acc);
      acc = fmaf(w4.y, hp[i2 + 1], acc);
      acc = fmaf(w4.z, hp[i2 + 2], acc);
      acc = fmaf(w4.w, hp[i2 + 3], acc);
    }
    red[threadIdx.x] = acc;
  }
  __syncthreads();
  if (threadIdx.x < V) {
    int o = threadIdx.x;
    float y = ((red[o*4] + red[o*4+1]) + (red[o*4+2] + red[o*4+3])) + be[o];
    yv[o] = y;
    if (mode == 1 && o < V - 1)
      out[((size_t)b * NDEC + j) * (V - 1) + o] = y;   // ys[:, :, :-1]
  }
  __syncthreads();

  // gumbel-hard argmax (first-index tie-break), wave 0 only
  if (threadIdx.x < V) {
    int o = threadIdx.x;
    float bv = yv[o] + noise[((size_t)b * NIT + iter) * V + o];
    int bi = o;
    #pragma unroll
    for (int m = 32; m >= 1; m >>= 1) {
      float ov = __shfl_xor(bv, m, 64);
      int   oi = __shfl_xor(bi, m, 64);
      if (ov > bv || (ov == bv && oi < bi)) { bv = ov; bi = oi; }
    }
    if (o == 0) s_idx = bi;
  }
  __syncthreads();
  int idx = s_idx;
  if (threadIdx.x < V && active)
    cur[b * V + threadIdx.x] = (threadIdx.x == idx) ? 1.0f : 0.0f;
  if (threadIdx.x == 0) {
    ib[16 + b] = active;   // scatter mask for this step
    ib[24 + b] = ptr;      // scatter base for this step
    if (active) ib[b] = (ptr + 1 == D1) ? 0 : ptr + 1;
    if (mode == 0) ib[8 + b] = dn | ((idx == 63) ? 1 : 0) | ((iter == 8) ? 1 : 0);
  }
}

} // anonymous namespace

extern "C" void kernel_launch(void* const* d_in, const int* in_sizes, int n_in,
                              void* d_out, int out_size, void* d_ws, size_t ws_size,
                              hipStream_t stream) {
  (void)in_sizes; (void)n_in; (void)out_size; (void)ws_size;
  const float* x   = (const float*)d_in[0];
  const float* wa  = (const float*)d_in[1];
  const float* ba  = (const float*)d_in[2];
  const float* lat = (const float*)d_in[3];
  const float* tau = (const float*)d_in[4];
  const float* we  = (const float*)d_in[5];
  const float* be  = (const float*)d_in[6];
  float* out = (float*)d_out;
  float* ws  = (float*)d_ws;

  k_init<<<dim3(256), dim3(256), 0, stream>>>(x, ws);

  for (int t = 0; t < T; ++t) {
    k_act_enc<<<dim3(B), dim3(256), 0, stream>>>(x, wa, ba, ws, t);
    k_scat<<<dim3(512), dim3(256), 0, stream>>>(tau, lat, ws, t % D1);
  }
  for (int it = 0; it < 9; ++it) {
    k_act_dec<<<dim3(B), dim3(256), 0, stream>>>(wa, ba, we, be, ws, out, it, 0, 0);
    k_scat<<<dim3(512), dim3(256), 0, stream>>>(tau, lat, ws, -1);
  }
  for (int j = 0; j < NDEC; ++j) {
    k_act_dec<<<dim3(B), dim3(256), 0, stream>>>(wa, ba, we, be, ws, out, 9 + j, 1, j);
    k_scat<<<dim3(512), dim3(256), 0, stream>>>(tau, lat, ws, -1);
  }
}